// Round 13
// baseline (166.430 us; speedup 1.0000x reference)
//
#include <hip/hip_runtime.h>
#include <hip/hip_bf16.h>
#include <math.h>

#define D_MODEL 512
#define N_HEADS 16
#define HEAD_DIM 32
#define T_SEQ 2048
#define B_SZ 2
#define NTOK (B_SZ * T_SEQ)        // 4096
#define QKV_DIM (3 * D_MODEL)      // 1536

#define LOG2_10000_D16 0.8304820237218405f
#define QSCALE_LOG2 0.2550348788f   // (1/sqrt(32)) * log2(e)
#define NROPE (T_SEQ * 16)          // 32768 (t, c) cos/sin entries

typedef short short8 __attribute__((ext_vector_type(8)));
typedef float f32x4  __attribute__((ext_vector_type(4)));

__device__ __forceinline__ float bf2f(unsigned int u16) {
    union { unsigned int i; float f; } v;
    v.i = u16 << 16;
    return v.f;
}

__device__ __forceinline__ unsigned short f2bf(float f) {   // RNE
    union { float f; unsigned int i; } v;
    v.f = f;
    unsigned int lsb = (v.i >> 16) & 1u;
    v.i += 0x7fffu + lsb;
    return (unsigned short)(v.i >> 16);
}

__device__ __forceinline__ unsigned int f2bf_tru32(float f) {  // bf16 in low 16, f >= 0
    union { float f; unsigned int i; } v;
    v.f = f;
    return v.i >> 16;
}

__device__ __forceinline__ void gld_lds16(const void* g, void* l) {
    __builtin_amdgcn_global_load_lds(
        (const __attribute__((address_space(1))) void*)g,
        (__attribute__((address_space(3))) void*)l, 16, 0, 0);
}

// single fused fp32->bf16 convert for x | w_qkv | w_o (float4 granules)
// + RoPE cos/sin table build (32768 entries) in the tail blocks
#define N4_X   (NTOK * D_MODEL / 4)            // 524288
#define N4_WQ  (QKV_DIM * D_MODEL / 4)         // 196608
#define N4_WO  (D_MODEL * D_MODEL / 4)         // 65536
__global__ __launch_bounds__(256) void cvt_all(const float* __restrict__ x,
                                               const float* __restrict__ wq,
                                               const float* __restrict__ wo,
                                               unsigned short* __restrict__ xb,
                                               unsigned short* __restrict__ wqb,
                                               unsigned short* __restrict__ wob,
                                               float2* __restrict__ rope) {
    int i = blockIdx.x * 256 + threadIdx.x;
    if (i >= N4_X + N4_WQ + N4_WO) {
        int kk = i - (N4_X + N4_WQ + N4_WO);
        if (kk < NROPE) {
            int t = kk >> 4, cd = kk & 15;
            float invf = exp2f(-LOG2_10000_D16 * (float)cd);
            float ss, cc;
            sincosf((float)t * invf, &ss, &cc);
            rope[kk] = make_float2(cc, ss);
        }
        return;
    }
    const float* in;
    unsigned short* out;
    int k;
    if (i < N4_X)                { in = x;  out = xb;  k = i; }
    else if (i < N4_X + N4_WQ)   { in = wq; out = wqb; k = i - N4_X; }
    else                         { in = wo; out = wob; k = i - N4_X - N4_WQ; }
    float4 v = ((const float4*)in)[k];
    ushort4 o;
    o.x = f2bf(v.x); o.y = f2bf(v.y); o.z = f2bf(v.z); o.w = f2bf(v.w);
    ((ushort4*)out)[k] = o;
}

// ---------------------------------------------------------------------------
// MT x 64 tile MFMA NT-GEMM (verified R0 structure, exact).
// ROPE epilogue: sec0 Q (rope+scale -> qb), sec1 K (rope -> kb swizzled),
// sec2 V (-> vt swizzled). cos/sin from precomputed table rope[t*16+c].
// ---------------------------------------------------------------------------
template<int MT, int LDA, int LDC, bool OUT_BF16, bool ROPE>
__global__ __launch_bounds__(256) void gemm_nt(const unsigned short* __restrict__ A,
                                               const unsigned short* __restrict__ B,
                                               void* __restrict__ Cout,
                                               unsigned short* __restrict__ kb,
                                               unsigned short* __restrict__ vt,
                                               const float2* __restrict__ rope) {
    __shared__ unsigned short Als[MT * 64];
    __shared__ unsigned short Bls[64 * 64];

    const int tid = threadIdx.x;
    const int m0 = blockIdx.y * MT;
    const int n0 = blockIdx.x * 64;

    const int wid  = tid >> 6;
    const int lane = tid & 63;
    const int c    = lane & 15;
    const int quad = lane >> 4;
    const int wm = (wid >> 1) * (MT / 2);
    const int wn = (wid & 1) * 32;
    const int MI = MT / 32;

    f32x4 acc[MI][2];
#pragma unroll
    for (int i = 0; i < MI; ++i)
#pragma unroll
        for (int j = 0; j < 2; ++j) acc[i][j] = (f32x4)0.f;

    const int srow = wid * 8 + (lane >> 3);
    const int schk = lane & 7;

    for (int k0 = 0; k0 < 512; k0 += 64) {
#pragma unroll
        for (int it = 0; it < MT / 32; ++it) {
            const unsigned short* g = A + (size_t)(m0 + it * 32 + srow) * LDA + k0 + schk * 8;
            gld_lds16(g, &Als[(it * 32 + srow) * 64 + schk * 8]);
        }
#pragma unroll
        for (int it = 0; it < 2; ++it) {
            const unsigned short* g = B + (size_t)(n0 + it * 32 + srow) * 512 + k0 + schk * 8;
            gld_lds16(g, &Bls[(it * 32 + srow) * 64 + schk * 8]);
        }
        __syncthreads();

#pragma unroll
        for (int kk = 0; kk < 2; ++kk) {
            short8 af[MI], bfr[2];
#pragma unroll
            for (int i = 0; i < MI; ++i)
                af[i] = *(const short8*)&Als[(wm + i * 16 + c) * 64 + kk * 32 + quad * 8];
#pragma unroll
            for (int j = 0; j < 2; ++j)
                bfr[j] = *(const short8*)&Bls[(wn + j * 16 + c) * 64 + kk * 32 + quad * 8];
#pragma unroll
            for (int i = 0; i < MI; ++i)
#pragma unroll
                for (int j = 0; j < 2; ++j)
                    acc[i][j] = __builtin_amdgcn_mfma_f32_16x16x32_bf16(af[i], bfr[j], acc[i][j], 0, 0, 0);
        }
        __syncthreads();
    }

    if (ROPE) {
        const int sec = n0 >> 9;     // 0 = Q, 1 = K, 2 = V
        if (sec == 0) {
            const float2* rp = rope + c;
#pragma unroll
            for (int i = 0; i < MI; ++i)
#pragma unroll
                for (int r = 0; r < 4; ++r) {
                    int t = (m0 + wm + i * 16 + quad * 4 + r) & (T_SEQ - 1);
                    float2 cs = rp[t * 16];
                    float e0 = acc[i][0][r], e1 = acc[i][1][r];
                    acc[i][0][r] = (e0 * cs.x - e1 * cs.y) * QSCALE_LOG2;
                    acc[i][1][r] = (e1 * cs.x + e0 * cs.y) * QSCALE_LOG2;
                }
            // falls through to generic bf16 writer -> qb (LDC = 512)
        } else if (sec == 1) {
            const float2* rp = rope + c;
            const int head = ((n0 - 512) + wn) >> 5;
#pragma unroll
            for (int i = 0; i < MI; ++i)
#pragma unroll
                for (int r = 0; r < 4; ++r) {
                    int mm = m0 + wm + i * 16 + quad * 4 + r;
                    int t = mm & (T_SEQ - 1);
                    float2 cs = rp[t * 16];
                    float e0 = acc[i][0][r], e1 = acc[i][1][r];
                    float k0v = e0 * cs.x - e1 * cs.y;     // d = c
                    float k1v = e1 * cs.x + e0 * cs.y;     // d = 16 + c
                    int bh = (mm >> 11) * 16 + head;
                    int s = (t & 3) ^ ((t >> 2) & 3);
                    unsigned short* row = kb + ((size_t)(bh * 2048 + t)) * 32;
                    row[((((c) >> 3) ^ s) << 3) + (c & 7)]        = f2bf(k0v);
                    row[((((16 + c) >> 3) ^ s) << 3) + (c & 7)]   = f2bf(k1v);
                }
            return;
        } else {
            // V -> vt[bh][d][t] with chunk swizzle; 4 acc rows = 4 consec t
#pragma unroll
            for (int i = 0; i < MI; ++i)
#pragma unroll
                for (int j = 0; j < 2; ++j) {
                    int nl = n0 - 1024 + wn + j * 16;
                    int head = nl >> 5;
                    int d = (nl & 16) + c;
                    int mm = m0 + wm + i * 16 + quad * 4;
                    int bI = mm >> 11;
                    int pos = mm & (T_SEQ - 1);
                    int phys = ((pos >> 3) & 7) ^ (d & 7);
                    size_t base = ((size_t)((bI * 16 + head) * 32 + d)) * 2048
                                  + (pos & ~63) + (phys << 3) + (pos & 7);
                    ushort4 st;
                    st.x = f2bf(acc[i][j][0]); st.y = f2bf(acc[i][j][1]);
                    st.z = f2bf(acc[i][j][2]); st.w = f2bf(acc[i][j][3]);
                    *(ushort4*)(vt + base) = st;
                }
            return;
        }
    }

    if (OUT_BF16) {
        unsigned short* Cb = (unsigned short*)Cout;
#pragma unroll
        for (int i = 0; i < MI; ++i)
#pragma unroll
            for (int j = 0; j < 2; ++j)
#pragma unroll
                for (int r = 0; r < 4; ++r) {
                    int mm = m0 + wm + i * 16 + quad * 4 + r;
                    int nn = n0 + wn + j * 16 + c;
                    Cb[(size_t)mm * LDC + nn] = f2bf(acc[i][j][r]);
                }
    } else {
        float* Cf = (float*)Cout;
#pragma unroll
        for (int i = 0; i < MI; ++i)
#pragma unroll
            for (int j = 0; j < 2; ++j)
#pragma unroll
                for (int r = 0; r < 4; ++r) {
                    int mm = m0 + wm + i * 16 + quad * 4 + r;
                    int nn = n0 + wn + j * 16 + c;
                    Cf[(size_t)mm * LDC + nn] = acc[i][j][r];
                }
    }
}

// ---------------------------------------------------------------------------
// Flash attention v13 (best measured, 118.3): v10 + setprio. UNCHANGED.
// ---------------------------------------------------------------------------
__global__ __launch_bounds__(256) void flash_attn(const unsigned short* __restrict__ qb,
                                                  const unsigned short* __restrict__ kb,
                                                  const unsigned short* __restrict__ vt,
                                                  unsigned short* __restrict__ ob) {
    __shared__ unsigned short KtL[64 * 32];   // [key][32 halves, chunk-swizzled]
    __shared__ unsigned short VtL[32 * 64];   // [d][64 halves, chunk-swizzled]
    __shared__ unsigned short Pl[4 * 16 * 72]; // per-wave 16 q-rows x 72 (64 keys + pad)

    const int idx   = blockIdx.x;             // 0..1023
    const int qtile = 31 - (idx >> 5);        // globally heavy first
    const int bh    = idx & 31;
    const int b = bh >> 4, h = bh & 15;
    const int tid  = threadIdx.x;
    const int wid  = tid >> 6;
    const int lane = tid & 63;
    const int c    = lane & 15;
    const int quad = lane >> 4;

    const int q0w = qtile * 64 + wid * 16;
    const int sK = (c & 3) ^ ((c >> 2) & 3);   // K chunk swizzle (key = j*16+c)
    const int sP = c & 7;                      // V chunk swizzle

    short8 qf = *(const short8*)(qb + ((size_t)(b * T_SEQ + q0w + c)) * 512 + h * HEAD_DIM + quad * 8);

    f32x4 accO[2];
    accO[0] = (f32x4)0.f; accO[1] = (f32x4)0.f;
    float l_part = 0.f;                        // partial denom for q = q0w + c

    unsigned short* plw = &Pl[wid * 16 * 72];

    // staging coordinates (match verified gld_lds16 lane-contiguous mapping)
    const int krow = tid >> 2, kch = tid & 3;
    const int vd   = tid >> 3, vch = tid & 7;
    const unsigned short* kbase = kb + (size_t)bh * 2048 * 32 + (size_t)krow * 32 + kch * 8;
    const unsigned short* vbase = vt + ((size_t)(bh * 32 + vd)) * 2048 + vch * 8;

    uint4 kreg = *(const uint4*)(kbase);
    uint4 vreg = *(const uint4*)(vbase);

    const int nkt = qtile + 1;
    for (int kt = 0; kt < nkt; ++kt) {
        __syncthreads();                    // prior compute done reading LDS
        *(uint4*)&KtL[tid * 8] = kreg;      // regs landed ~1 full iter ago
        *(uint4*)&VtL[tid * 8] = vreg;
        __syncthreads();                    // staging visible

        if (kt + 1 < nkt) {                 // prefetch next tile into regs
            kreg = *(const uint4*)(kbase + (size_t)(kt + 1) * 64 * 32);
            vreg = *(const uint4*)(vbase + (kt + 1) * 64);
        }

        // --- S^T = K.Q^T : sv[j][r] = S[key=j*16+quad*4+r][q=q0w+c] ---
        f32x4 sv[4];
        __builtin_amdgcn_s_setprio(1);
#pragma unroll
        for (int j = 0; j < 4; ++j) {
            short8 kf = *(const short8*)&KtL[(j * 16 + c) * 32 + ((quad ^ sK) << 3)];
            f32x4 z = (f32x4)0.f;
            sv[j] = __builtin_amdgcn_mfma_f32_16x16x32_bf16(kf, qf, z, 0, 0, 0);
        }
        __builtin_amdgcn_s_setprio(0);

        if (kt == qtile) {                  // causal: mask key > q
#pragma unroll
            for (int j = 0; j < 4; ++j)
#pragma unroll
                for (int r = 0; r < 4; ++r)
                    if (j * 16 + quad * 4 + r > wid * 16 + c) sv[j][r] = -30000.f;
        }

        // --- static softmax base-2; P -> LDS rows [q][key], b64 writes ---
#pragma unroll
        for (int j = 0; j < 4; ++j) {
            float p0 = exp2f(sv[j][0]);
            float p1 = exp2f(sv[j][1]);
            float p2 = exp2f(sv[j][2]);
            float p3 = exp2f(sv[j][3]);
            l_part += (p0 + p1) + (p2 + p3);
            unsigned int w0 = f2bf_tru32(p0) | (f2bf_tru32(p1) << 16);
            unsigned int w1 = f2bf_tru32(p2) | (f2bf_tru32(p3) << 16);
            uint2 w = make_uint2(w0, w1);
            *(uint2*)&plw[c * 72 + j * 16 + quad * 4] = w;   // ushort idx = key
        }

        // --- PV : A = P[q][k] (row q=c frag), B = V ---
        __builtin_amdgcn_s_setprio(1);
#pragma unroll
        for (int kk = 0; kk < 2; ++kk) {
            short8 pf = *(const short8*)&plw[c * 72 + kk * 32 + quad * 8];
#pragma unroll
            for (int ns = 0; ns < 2; ++ns) {
                short8 vf = *(const short8*)&VtL[(ns * 16 + c) * 64 + (((kk * 4 + quad) ^ sP) << 3)];
                accO[ns] = __builtin_amdgcn_mfma_f32_16x16x32_bf16(pf, vf, accO[ns], 0, 0, 0);
            }
        }
        __builtin_amdgcn_s_setprio(0);
    }

    // --- epilogue: l lives per q=c; reduce across quads, redistribute ---
    float lr = l_part;
    lr += __shfl_xor(lr, 16);
    lr += __shfl_xor(lr, 32);               // lane (c,quad) holds l[q0w + c]
#pragma unroll
    for (int r = 0; r < 4; ++r) {
        float lq = __shfl(lr, quad * 4 + r);    // l for q-local = quad*4+r
        float inv = 1.f / lq;
        int qg = q0w + quad * 4 + r;
        unsigned short* op = ob + ((size_t)(b * T_SEQ + qg)) * 512 + h * HEAD_DIM;
#pragma unroll
        for (int ns = 0; ns < 2; ++ns)
            op[ns * 16 + c] = f2bf(accO[ns][r] * inv);
    }
}

extern "C" void kernel_launch(void* const* d_in, const int* in_sizes, int n_in,
                              void* d_out, int out_size, void* d_ws, size_t ws_size,
                              hipStream_t stream) {
    const float* x     = (const float*)d_in[0];
    const float* w_qkv = (const float*)d_in[1];
    const float* w_o   = (const float*)d_in[2];
    float* out = (float*)d_out;

    // workspace (ushorts): qb 4MB | kb 4 | vt 4 | xb 4 | wqb 1.5 | wob 0.5 | ob 4 | rope 256KB
    unsigned short* qb  = (unsigned short*)d_ws;
    unsigned short* kb  = qb  + (size_t)NTOK * D_MODEL;
    unsigned short* vt  = kb  + (size_t)32 * 2048 * 32;
    unsigned short* xb  = vt  + (size_t)32 * 32 * 2048;
    unsigned short* wqb = xb  + (size_t)NTOK * D_MODEL;
    unsigned short* wob = wqb + (size_t)QKV_DIM * D_MODEL;
    unsigned short* ob  = wob + (size_t)D_MODEL * D_MODEL;
    float2*         rope = (float2*)(ob + (size_t)NTOK * D_MODEL);

    {
        int total = N4_X + N4_WQ + N4_WO + NROPE;
        cvt_all<<<(total + 255) / 256, 256, 0, stream>>>(x, w_qkv, w_o, xb, wqb, wob, rope);
    }
    // QKV projection: MEASUREMENT — launched 3x (idempotent; deterministic
    // outputs from xb/wqb each replay). T_QKV+T_out = (dur - 118.3)/2.
    {
        dim3 grid(QKV_DIM / 64, NTOK / 128);   // (24, 32) = 768 blocks
        gemm_nt<128, D_MODEL, D_MODEL, true, true><<<grid, 256, 0, stream>>>(xb, wqb, qb, kb, vt, rope);
        gemm_nt<128, D_MODEL, D_MODEL, true, true><<<grid, 256, 0, stream>>>(xb, wqb, qb, kb, vt, rope);
        gemm_nt<128, D_MODEL, D_MODEL, true, true><<<grid, 256, 0, stream>>>(xb, wqb, qb, kb, vt, rope);
    }
    // Flash: 1024 blocks, globally heavy-first (v13, UNCHANGED best)
    {
        flash_attn<<<1024, 256, 0, stream>>>(qb, kb, vt, ob);
    }
    // Output projection: MEASUREMENT — launched 3x (idempotent)
    {
        dim3 grid(D_MODEL / 64, NTOK / 64);   // (8, 64) = 512 blocks
        gemm_nt<64, D_MODEL, D_MODEL, false, false><<<grid, 256, 0, stream>>>(ob, wob, out, nullptr, nullptr, nullptr);
        gemm_nt<64, D_MODEL, D_MODEL, false, false><<<grid, 256, 0, stream>>>(ob, wob, out, nullptr, nullptr, nullptr);
        gemm_nt<64, D_MODEL, D_MODEL, false, false><<<grid, 256, 0, stream>>>(ob, wob, out, nullptr, nullptr, nullptr);
    }
}

// Round 14
// 117.970 us; speedup vs baseline: 1.4108x; 1.4108x over previous
//
#include <hip/hip_runtime.h>
#include <hip/hip_bf16.h>
#include <math.h>

#define D_MODEL 512
#define N_HEADS 16
#define HEAD_DIM 32
#define T_SEQ 2048
#define B_SZ 2
#define NTOK (B_SZ * T_SEQ)        // 4096
#define QKV_DIM (3 * D_MODEL)      // 1536

#define LOG2_10000_D16 0.8304820237218405f
#define QSCALE_LOG2 0.2550348788f   // (1/sqrt(32)) * log2(e)
#define NROPE (T_SEQ * 16)          // 32768 (t, c) cos/sin entries

typedef short short8 __attribute__((ext_vector_type(8)));
typedef float f32x4  __attribute__((ext_vector_type(4)));

__device__ __forceinline__ float bf2f(unsigned int u16) {
    union { unsigned int i; float f; } v;
    v.i = u16 << 16;
    return v.f;
}

__device__ __forceinline__ unsigned short f2bf(float f) {   // RNE
    union { float f; unsigned int i; } v;
    v.f = f;
    unsigned int lsb = (v.i >> 16) & 1u;
    v.i += 0x7fffu + lsb;
    return (unsigned short)(v.i >> 16);
}

__device__ __forceinline__ unsigned int f2bf_tru32(float f) {  // bf16 in low 16, f >= 0
    union { float f; unsigned int i; } v;
    v.f = f;
    return v.i >> 16;
}

__device__ __forceinline__ void gld_lds16(const void* g, void* l) {
    __builtin_amdgcn_global_load_lds(
        (const __attribute__((address_space(1))) void*)g,
        (__attribute__((address_space(3))) void*)l, 16, 0, 0);
}

// single fused fp32->bf16 convert for x | w_qkv | w_o (float4 granules)
// + RoPE cos/sin table build (32768 entries) in the tail blocks
#define N4_X   (NTOK * D_MODEL / 4)            // 524288
#define N4_WQ  (QKV_DIM * D_MODEL / 4)         // 196608
#define N4_WO  (D_MODEL * D_MODEL / 4)         // 65536
__global__ __launch_bounds__(256) void cvt_all(const float* __restrict__ x,
                                               const float* __restrict__ wq,
                                               const float* __restrict__ wo,
                                               unsigned short* __restrict__ xb,
                                               unsigned short* __restrict__ wqb,
                                               unsigned short* __restrict__ wob,
                                               float2* __restrict__ rope) {
    int i = blockIdx.x * 256 + threadIdx.x;
    if (i >= N4_X + N4_WQ + N4_WO) {
        int kk = i - (N4_X + N4_WQ + N4_WO);
        if (kk < NROPE) {
            int t = kk >> 4, cd = kk & 15;
            float invf = exp2f(-LOG2_10000_D16 * (float)cd);
            float ss, cc;
            sincosf((float)t * invf, &ss, &cc);
            rope[kk] = make_float2(cc, ss);
        }
        return;
    }
    const float* in;
    unsigned short* out;
    int k;
    if (i < N4_X)                { in = x;  out = xb;  k = i; }
    else if (i < N4_X + N4_WQ)   { in = wq; out = wqb; k = i - N4_X; }
    else                         { in = wo; out = wob; k = i - N4_X - N4_WQ; }
    float4 v = ((const float4*)in)[k];
    ushort4 o;
    o.x = f2bf(v.x); o.y = f2bf(v.y); o.z = f2bf(v.z); o.w = f2bf(v.w);
    ((ushort4*)out)[k] = o;
}

// ---------------------------------------------------------------------------
// MT x 64 tile MFMA NT-GEMM (verified R0 structure, exact).
// ROPE epilogue: sec0 Q (rope+scale -> qb), sec1 K (rope -> kb swizzled),
// sec2 V (-> vt swizzled). cos/sin from precomputed table rope[t*16+c].
// ---------------------------------------------------------------------------
template<int MT, int LDA, int LDC, bool OUT_BF16, bool ROPE>
__global__ __launch_bounds__(256) void gemm_nt(const unsigned short* __restrict__ A,
                                               const unsigned short* __restrict__ B,
                                               void* __restrict__ Cout,
                                               unsigned short* __restrict__ kb,
                                               unsigned short* __restrict__ vt,
                                               const float2* __restrict__ rope) {
    __shared__ unsigned short Als[MT * 64];
    __shared__ unsigned short Bls[64 * 64];

    const int tid = threadIdx.x;
    const int m0 = blockIdx.y * MT;
    const int n0 = blockIdx.x * 64;

    const int wid  = tid >> 6;
    const int lane = tid & 63;
    const int c    = lane & 15;
    const int quad = lane >> 4;
    const int wm = (wid >> 1) * (MT / 2);
    const int wn = (wid & 1) * 32;
    const int MI = MT / 32;

    f32x4 acc[MI][2];
#pragma unroll
    for (int i = 0; i < MI; ++i)
#pragma unroll
        for (int j = 0; j < 2; ++j) acc[i][j] = (f32x4)0.f;

    const int srow = wid * 8 + (lane >> 3);
    const int schk = lane & 7;

    for (int k0 = 0; k0 < 512; k0 += 64) {
#pragma unroll
        for (int it = 0; it < MT / 32; ++it) {
            const unsigned short* g = A + (size_t)(m0 + it * 32 + srow) * LDA + k0 + schk * 8;
            gld_lds16(g, &Als[(it * 32 + srow) * 64 + schk * 8]);
        }
#pragma unroll
        for (int it = 0; it < 2; ++it) {
            const unsigned short* g = B + (size_t)(n0 + it * 32 + srow) * 512 + k0 + schk * 8;
            gld_lds16(g, &Bls[(it * 32 + srow) * 64 + schk * 8]);
        }
        __syncthreads();

#pragma unroll
        for (int kk = 0; kk < 2; ++kk) {
            short8 af[MI], bfr[2];
#pragma unroll
            for (int i = 0; i < MI; ++i)
                af[i] = *(const short8*)&Als[(wm + i * 16 + c) * 64 + kk * 32 + quad * 8];
#pragma unroll
            for (int j = 0; j < 2; ++j)
                bfr[j] = *(const short8*)&Bls[(wn + j * 16 + c) * 64 + kk * 32 + quad * 8];
#pragma unroll
            for (int i = 0; i < MI; ++i)
#pragma unroll
                for (int j = 0; j < 2; ++j)
                    acc[i][j] = __builtin_amdgcn_mfma_f32_16x16x32_bf16(af[i], bfr[j], acc[i][j], 0, 0, 0);
        }
        __syncthreads();
    }

    if (ROPE) {
        const int sec = n0 >> 9;     // 0 = Q, 1 = K, 2 = V
        if (sec == 0) {
            const float2* rp = rope + c;
#pragma unroll
            for (int i = 0; i < MI; ++i)
#pragma unroll
                for (int r = 0; r < 4; ++r) {
                    int t = (m0 + wm + i * 16 + quad * 4 + r) & (T_SEQ - 1);
                    float2 cs = rp[t * 16];
                    float e0 = acc[i][0][r], e1 = acc[i][1][r];
                    acc[i][0][r] = (e0 * cs.x - e1 * cs.y) * QSCALE_LOG2;
                    acc[i][1][r] = (e1 * cs.x + e0 * cs.y) * QSCALE_LOG2;
                }
            // falls through to generic bf16 writer -> qb (LDC = 512)
        } else if (sec == 1) {
            const float2* rp = rope + c;
            const int head = ((n0 - 512) + wn) >> 5;
#pragma unroll
            for (int i = 0; i < MI; ++i)
#pragma unroll
                for (int r = 0; r < 4; ++r) {
                    int mm = m0 + wm + i * 16 + quad * 4 + r;
                    int t = mm & (T_SEQ - 1);
                    float2 cs = rp[t * 16];
                    float e0 = acc[i][0][r], e1 = acc[i][1][r];
                    float k0v = e0 * cs.x - e1 * cs.y;     // d = c
                    float k1v = e1 * cs.x + e0 * cs.y;     // d = 16 + c
                    int bh = (mm >> 11) * 16 + head;
                    int s = (t & 3) ^ ((t >> 2) & 3);
                    unsigned short* row = kb + ((size_t)(bh * 2048 + t)) * 32;
                    row[((((c) >> 3) ^ s) << 3) + (c & 7)]        = f2bf(k0v);
                    row[((((16 + c) >> 3) ^ s) << 3) + (c & 7)]   = f2bf(k1v);
                }
            return;
        } else {
            // V -> vt[bh][d][t] with chunk swizzle; 4 acc rows = 4 consec t
#pragma unroll
            for (int i = 0; i < MI; ++i)
#pragma unroll
                for (int j = 0; j < 2; ++j) {
                    int nl = n0 - 1024 + wn + j * 16;
                    int head = nl >> 5;
                    int d = (nl & 16) + c;
                    int mm = m0 + wm + i * 16 + quad * 4;
                    int bI = mm >> 11;
                    int pos = mm & (T_SEQ - 1);
                    int phys = ((pos >> 3) & 7) ^ (d & 7);
                    size_t base = ((size_t)((bI * 16 + head) * 32 + d)) * 2048
                                  + (pos & ~63) + (phys << 3) + (pos & 7);
                    ushort4 st;
                    st.x = f2bf(acc[i][j][0]); st.y = f2bf(acc[i][j][1]);
                    st.z = f2bf(acc[i][j][2]); st.w = f2bf(acc[i][j][3]);
                    *(ushort4*)(vt + base) = st;
                }
            return;
        }
    }

    if (OUT_BF16) {
        unsigned short* Cb = (unsigned short*)Cout;
#pragma unroll
        for (int i = 0; i < MI; ++i)
#pragma unroll
            for (int j = 0; j < 2; ++j)
#pragma unroll
                for (int r = 0; r < 4; ++r) {
                    int mm = m0 + wm + i * 16 + quad * 4 + r;
                    int nn = n0 + wn + j * 16 + c;
                    Cb[(size_t)mm * LDC + nn] = f2bf(acc[i][j][r]);
                }
    } else {
        float* Cf = (float*)Cout;
#pragma unroll
        for (int i = 0; i < MI; ++i)
#pragma unroll
            for (int j = 0; j < 2; ++j)
#pragma unroll
                for (int r = 0; r < 4; ++r) {
                    int mm = m0 + wm + i * 16 + quad * 4 + r;
                    int nn = n0 + wn + j * 16 + c;
                    Cf[(size_t)mm * LDC + nn] = acc[i][j][r];
                }
    }
}

// ---------------------------------------------------------------------------
// Flash attention v13 (best measured, 118.3): v10 structure + setprio.
//  * swapped QK^T: sv[j][r] = S[key=j*16+quad*4+r][q=q0w+c]
//  * P stored [q][key] rows padded to 72 ushorts; 4x ds_write_b64 in,
//    2x ds_read_b128 out
//  * 2-barrier staging loop + register prefetch (LDS staging REQUIRED —
//    v12 proved direct-L2 fragment reads are uncoalesced, 2.2x regression)
// ---------------------------------------------------------------------------
__global__ __launch_bounds__(256) void flash_attn(const unsigned short* __restrict__ qb,
                                                  const unsigned short* __restrict__ kb,
                                                  const unsigned short* __restrict__ vt,
                                                  unsigned short* __restrict__ ob) {
    __shared__ unsigned short KtL[64 * 32];   // [key][32 halves, chunk-swizzled]
    __shared__ unsigned short VtL[32 * 64];   // [d][64 halves, chunk-swizzled]
    __shared__ unsigned short Pl[4 * 16 * 72]; // per-wave 16 q-rows x 72 (64 keys + pad)

    const int idx   = blockIdx.x;             // 0..1023
    const int qtile = 31 - (idx >> 5);        // globally heavy first
    const int bh    = idx & 31;
    const int b = bh >> 4, h = bh & 15;
    const int tid  = threadIdx.x;
    const int wid  = tid >> 6;
    const int lane = tid & 63;
    const int c    = lane & 15;
    const int quad = lane >> 4;

    const int q0w = qtile * 64 + wid * 16;
    const int sK = (c & 3) ^ ((c >> 2) & 3);   // K chunk swizzle (key = j*16+c)
    const int sP = c & 7;                      // V chunk swizzle

    short8 qf = *(const short8*)(qb + ((size_t)(b * T_SEQ + q0w + c)) * 512 + h * HEAD_DIM + quad * 8);

    f32x4 accO[2];
    accO[0] = (f32x4)0.f; accO[1] = (f32x4)0.f;
    float l_part = 0.f;                        // partial denom for q = q0w + c

    unsigned short* plw = &Pl[wid * 16 * 72];

    // staging coordinates (match verified gld_lds16 lane-contiguous mapping)
    const int krow = tid >> 2, kch = tid & 3;
    const int vd   = tid >> 3, vch = tid & 7;
    const unsigned short* kbase = kb + (size_t)bh * 2048 * 32 + (size_t)krow * 32 + kch * 8;
    const unsigned short* vbase = vt + ((size_t)(bh * 32 + vd)) * 2048 + vch * 8;

    uint4 kreg = *(const uint4*)(kbase);
    uint4 vreg = *(const uint4*)(vbase);

    const int nkt = qtile + 1;
    for (int kt = 0; kt < nkt; ++kt) {
        __syncthreads();                    // prior compute done reading LDS
        *(uint4*)&KtL[tid * 8] = kreg;      // regs landed ~1 full iter ago
        *(uint4*)&VtL[tid * 8] = vreg;
        __syncthreads();                    // staging visible

        if (kt + 1 < nkt) {                 // prefetch next tile into regs
            kreg = *(const uint4*)(kbase + (size_t)(kt + 1) * 64 * 32);
            vreg = *(const uint4*)(vbase + (kt + 1) * 64);
        }

        // --- S^T = K.Q^T : sv[j][r] = S[key=j*16+quad*4+r][q=q0w+c] ---
        f32x4 sv[4];
        __builtin_amdgcn_s_setprio(1);
#pragma unroll
        for (int j = 0; j < 4; ++j) {
            short8 kf = *(const short8*)&KtL[(j * 16 + c) * 32 + ((quad ^ sK) << 3)];
            f32x4 z = (f32x4)0.f;
            sv[j] = __builtin_amdgcn_mfma_f32_16x16x32_bf16(kf, qf, z, 0, 0, 0);
        }
        __builtin_amdgcn_s_setprio(0);

        if (kt == qtile) {                  // causal: mask key > q
#pragma unroll
            for (int j = 0; j < 4; ++j)
#pragma unroll
                for (int r = 0; r < 4; ++r)
                    if (j * 16 + quad * 4 + r > wid * 16 + c) sv[j][r] = -30000.f;
        }

        // --- static softmax base-2; P -> LDS rows [q][key], b64 writes ---
#pragma unroll
        for (int j = 0; j < 4; ++j) {
            float p0 = exp2f(sv[j][0]);
            float p1 = exp2f(sv[j][1]);
            float p2 = exp2f(sv[j][2]);
            float p3 = exp2f(sv[j][3]);
            l_part += (p0 + p1) + (p2 + p3);
            unsigned int w0 = f2bf_tru32(p0) | (f2bf_tru32(p1) << 16);
            unsigned int w1 = f2bf_tru32(p2) | (f2bf_tru32(p3) << 16);
            uint2 w = make_uint2(w0, w1);
            *(uint2*)&plw[c * 72 + j * 16 + quad * 4] = w;   // ushort idx = key
        }

        // --- PV : A = P[q][k] (row q=c frag), B = V ---
        __builtin_amdgcn_s_setprio(1);
#pragma unroll
        for (int kk = 0; kk < 2; ++kk) {
            short8 pf = *(const short8*)&plw[c * 72 + kk * 32 + quad * 8];
#pragma unroll
            for (int ns = 0; ns < 2; ++ns) {
                short8 vf = *(const short8*)&VtL[(ns * 16 + c) * 64 + (((kk * 4 + quad) ^ sP) << 3)];
                accO[ns] = __builtin_amdgcn_mfma_f32_16x16x32_bf16(pf, vf, accO[ns], 0, 0, 0);
            }
        }
        __builtin_amdgcn_s_setprio(0);
    }

    // --- epilogue: l lives per q=c; reduce across quads, redistribute ---
    float lr = l_part;
    lr += __shfl_xor(lr, 16);
    lr += __shfl_xor(lr, 32);               // lane (c,quad) holds l[q0w + c]
#pragma unroll
    for (int r = 0; r < 4; ++r) {
        float lq = __shfl(lr, quad * 4 + r);    // l for q-local = quad*4+r
        float inv = 1.f / lq;
        int qg = q0w + quad * 4 + r;
        unsigned short* op = ob + ((size_t)(b * T_SEQ + qg)) * 512 + h * HEAD_DIM;
#pragma unroll
        for (int ns = 0; ns < 2; ++ns)
            op[ns * 16 + c] = f2bf(accO[ns][r] * inv);
    }
}

extern "C" void kernel_launch(void* const* d_in, const int* in_sizes, int n_in,
                              void* d_out, int out_size, void* d_ws, size_t ws_size,
                              hipStream_t stream) {
    const float* x     = (const float*)d_in[0];
    const float* w_qkv = (const float*)d_in[1];
    const float* w_o   = (const float*)d_in[2];
    float* out = (float*)d_out;

    // workspace (ushorts): qb 4MB | kb 4 | vt 4 | xb 4 | wqb 1.5 | wob 0.5 | ob 4 | rope 256KB
    unsigned short* qb  = (unsigned short*)d_ws;
    unsigned short* kb  = qb  + (size_t)NTOK * D_MODEL;
    unsigned short* vt  = kb  + (size_t)32 * 2048 * 32;
    unsigned short* xb  = vt  + (size_t)32 * 32 * 2048;
    unsigned short* wqb = xb  + (size_t)NTOK * D_MODEL;
    unsigned short* wob = wqb + (size_t)QKV_DIM * D_MODEL;
    unsigned short* ob  = wob + (size_t)D_MODEL * D_MODEL;
    float2*         rope = (float2*)(ob + (size_t)NTOK * D_MODEL);

    {
        int total = N4_X + N4_WQ + N4_WO + NROPE;
        cvt_all<<<(total + 255) / 256, 256, 0, stream>>>(x, w_qkv, w_o, xb, wqb, wob, rope);
    }
    // QKV projection + fused RoPE/scale; Q->qb, K->kb (swizzled), V->vt (swizzled)
    {
        dim3 grid(QKV_DIM / 64, NTOK / 128);   // (24, 32) = 768 blocks
        gemm_nt<128, D_MODEL, D_MODEL, true, true><<<grid, 256, 0, stream>>>(xb, wqb, qb, kb, vt, rope);
    }
    // Flash: 1024 blocks, globally heavy-first (v13 best)
    {
        flash_attn<<<1024, 256, 0, stream>>>(qb, kb, vt, ob);
    }
    // Output projection (A = attn in ob, lda 512) -> fp32 out
    {
        dim3 grid(D_MODEL / 64, NTOK / 64);   // (8, 64) = 512 blocks
        gemm_nt<64, D_MODEL, D_MODEL, false, false><<<grid, 256, 0, stream>>>(ob, wob, out, nullptr, nullptr, nullptr);
    }
}